// Round 3
// baseline (46.312 us; speedup 1.0000x reference)
//
#include <hip/hip_runtime.h>

// DIN scorer, fused single kernel, fully collapsed epilogue:
//   V[j,h] = W1[1152+j*36+h] + sum_i k_i W1[2304+1152*i+j*36+h]   (bf16 LDS V16)
//   cpre[h] = -(b1[h] + sum_i k_i W1[i*36+h]) * LOG2E              (merged in Phase B)
//   Z = Q(200x32).V(32x36) via swapped mfma_f32_16x16x32_bf16: D[row=h,col=n]
//   w[n] = b2 + sum_h sigmoid(Z)*W2[h]   -> known per-lane right after 2 shfls,
//   out[col] accumulated IN the tile loop from the same fp32 fragments (no w_s,
//   no butterfly, no goods re-read, no rr held across kernel).

#define BB 1024
#define NN 200
#define KK 32
#define HID 36
#define QP 40
#define LOG2E 1.44269504f

typedef __attribute__((ext_vector_type(8))) short bf16x8;
typedef __attribute__((ext_vector_type(4))) float f32x4;

__device__ __forceinline__ float rfl(float x) {
    return __uint_as_float(__builtin_amdgcn_readfirstlane(__float_as_uint(x)));
}
__device__ __forceinline__ unsigned short f2bf(float x) {   // RNE f32->bf16
    unsigned int u = __float_as_uint(x);
    u = (u + 0x7fffu + ((u >> 16) & 1u)) >> 16;
    return (unsigned short)u;
}
__device__ __forceinline__ unsigned int pk_bf16(float lo, float hi) { // RNE pack
    unsigned int r;
    asm("v_cvt_pk_bf16_f32 %0, %1, %2" : "=v"(r) : "v"(lo), "v"(hi));
    return r;
}
__device__ __forceinline__ float fast_rcp(float x) {
#if __has_builtin(__builtin_amdgcn_rcpf)
    return __builtin_amdgcn_rcpf(x);
#else
    return 1.0f / x;
#endif
}
__device__ __forceinline__ float fast_exp2(float x) {
#if __has_builtin(__builtin_amdgcn_exp2f)
    return __builtin_amdgcn_exp2f(x);
#else
    return exp2f(x);
#endif
}

__global__ __launch_bounds__(256, 6) void din_kernel(
    const float* __restrict__ cad,    // [B,K]
    const float* __restrict__ goods,  // [B,N,K]
    const float* __restrict__ W1,     // [1088*36]
    const float* __restrict__ b1,     // [36]
    const float* __restrict__ W2,     // [36]
    const float* __restrict__ b2,     // [1]
    float* __restrict__ out)          // [B,K]
{
    __shared__ alignas(16) unsigned short V16[48 * QP];   // [h][j] bf16, rows 36..47 zero
    __shared__ alignas(16) float c48[48];                 // -c*LOG2E, padded 0
    __shared__ alignas(16) float w248[48];                // W2 padded 0
    __shared__ alignas(16) float red_s[4 * KK];

    const int tid  = threadIdx.x;
    const int b    = blockIdx.x;
    const int lane = tid & 63;
    const int wv   = tid >> 6;
    const int l15  = lane & 15, lk = lane >> 4;

    // ---- k -> SGPRs (critical for Phase B; issue first) ----
    const float4* kb4 = reinterpret_cast<const float4*>(cad + b * KK);
    float ks[KK];
    #pragma unroll
    for (int t = 0; t < 8; ++t) {
        const float4 kv = kb4[t];
        ks[4*t+0] = rfl(kv.x); ks[4*t+1] = rfl(kv.y);
        ks[4*t+2] = rfl(kv.z); ks[4*t+3] = rfl(kv.w);
    }
    const float b2v = rfl(b2[0]);

    // ---- goods fragment prefetch: THE HBM stream (each elem read exactly once) ----
    const float* gb = goods + (size_t)b * NN * KK;
    float4 fqa[4], fqb[4];
    #pragma unroll
    for (int t = 0; t < 4; ++t) {
        const int m = wv + 4 * t;
        if (m < 13) {
            int row = m * 16 + l15;
            row = (row < NN) ? row : (NN - 1);
            const float4* qp = reinterpret_cast<const float4*>(gb + row * KK + lk * 8);
            fqa[t] = qp[0];
            fqb[t] = qp[1];
        }
    }

    // ---- Phase B: V (288 float4) + c (9 float4) in one i-loop ----
    {
        const float4* W1q = reinterpret_cast<const float4*>(W1);
        float4 acc0 = W1q[288 + tid];                       // bias rows (W1+1152)
        const bool has1 = (tid < 32);
        const bool hasC = (tid >= 32) && (tid < 41);
        const int  hq   = tid - 32;
        float4 acc1 = make_float4(0.f, 0.f, 0.f, 0.f);
        float4 accC = make_float4(0.f, 0.f, 0.f, 0.f);
        if (has1) acc1 = W1q[288 + 256 + tid];
        if (hasC) accC = reinterpret_cast<const float4*>(b1)[hq];

        #pragma unroll 4
        for (int i = 0; i < KK; ++i) {
            const float ki = ks[i];
            const float4* W1o = W1q + 576 + 288 * i;        // W1 + 2304 + 1152*i
            const float4 w0 = W1o[tid];
            acc0.x += ki * w0.x; acc0.y += ki * w0.y;
            acc0.z += ki * w0.z; acc0.w += ki * w0.w;
            if (has1) {
                const float4 w1v = W1o[256 + tid];
                acc1.x += ki * w1v.x; acc1.y += ki * w1v.y;
                acc1.z += ki * w1v.z; acc1.w += ki * w1v.w;
            }
            if (hasC) {
                const float4 wc = W1q[i * 9 + hq];          // W1[i*36 + 4*hq ..]
                accC.x += ki * wc.x; accC.y += ki * wc.y;
                accC.z += ki * wc.z; accC.w += ki * wc.w;
            }
        }

        // scatter V -> bf16 LDS
        {
            const float a0[4] = {acc0.x, acc0.y, acc0.z, acc0.w};
            #pragma unroll
            for (int q = 0; q < 4; ++q) {
                const int e = 4 * tid + q, j = e / 36, h = e - 36 * j;
                V16[h * QP + j] = f2bf(a0[q]);
            }
            if (has1) {
                const float a1[4] = {acc1.x, acc1.y, acc1.z, acc1.w};
                #pragma unroll
                for (int q = 0; q < 4; ++q) {
                    const int e = 1024 + 4 * tid + q, j = e / 36, h = e - 36 * j;
                    V16[h * QP + j] = f2bf(a1[q]);
                }
            }
        }
        // c (premultiplied by -LOG2E), pads, W2 copy + pads
        if (hasC) {
            float4 cp4;
            cp4.x = -accC.x * LOG2E; cp4.y = -accC.y * LOG2E;
            cp4.z = -accC.z * LOG2E; cp4.w = -accC.w * LOG2E;
            *reinterpret_cast<float4*>(&c48[4 * hq]) = cp4;
        }
        if (tid >= 41 && tid < 44)
            *reinterpret_cast<float4*>(&c48[36 + 4 * (tid - 41)]) =
                make_float4(0.f, 0.f, 0.f, 0.f);
        if (tid >= 44 && tid < 53)
            *reinterpret_cast<float4*>(&w248[4 * (tid - 44)]) =
                reinterpret_cast<const float4*>(W2)[tid - 44];
        if (tid >= 53 && tid < 56)
            *reinterpret_cast<float4*>(&w248[36 + 4 * (tid - 53)]) =
                make_float4(0.f, 0.f, 0.f, 0.f);
        // V16 pad rows h=36..47 (j 0..31)
        if (tid < 192) {
            unsigned int* v32 = reinterpret_cast<unsigned int*>(V16);
            v32[(36 + (tid >> 4)) * (QP / 2) + (tid & 15)] = 0u;
        }
    }
    __syncthreads();   // V16, c48, w248 ready

    // ---- per-lane V fragments (MFMA A-operand) ----
    bf16x8 bfrag[3];
    #pragma unroll
    for (int nt = 0; nt < 3; ++nt)
        bfrag[nt] = *reinterpret_cast<const bf16x8*>(&V16[(nt * 16 + l15) * QP + lk * 8]);

    // ---- tile loop: MFMA -> sigmoid -> w_n -> fused out-accumulation ----
    float facc[8] = {0.f, 0.f, 0.f, 0.f, 0.f, 0.f, 0.f, 0.f};
    #pragma unroll
    for (int t = 0; t < 4; ++t) {
        const int m = wv + 4 * t;
        if (m < 13) {
            union { unsigned int u[4]; bf16x8 v; } aq;
            aq.u[0] = pk_bf16(fqa[t].x, fqa[t].y);
            aq.u[1] = pk_bf16(fqa[t].z, fqa[t].w);
            aq.u[2] = pk_bf16(fqb[t].x, fqb[t].y);
            aq.u[3] = pk_bf16(fqb[t].z, fqb[t].w);
            const f32x4 zero = {0.f, 0.f, 0.f, 0.f};
            const f32x4 d0 = __builtin_amdgcn_mfma_f32_16x16x32_bf16(bfrag[0], aq.v, zero, 0, 0, 0);
            const f32x4 d1 = __builtin_amdgcn_mfma_f32_16x16x32_bf16(bfrag[1], aq.v, zero, 0, 0, 0);
            const f32x4 d2 = __builtin_amdgcn_mfma_f32_16x16x32_bf16(bfrag[2], aq.v, zero, 0, 0, 0);

            const f32x4 c0 = *reinterpret_cast<const f32x4*>(&c48[lk * 4]);
            const f32x4 w0 = *reinterpret_cast<const f32x4*>(&w248[lk * 4]);
            const f32x4 c1 = *reinterpret_cast<const f32x4*>(&c48[16 + lk * 4]);
            const f32x4 w1 = *reinterpret_cast<const f32x4*>(&w248[16 + lk * 4]);
            const f32x4 c2 = *reinterpret_cast<const f32x4*>(&c48[32 + lk * 4]);
            const f32x4 w2 = *reinterpret_cast<const f32x4*>(&w248[32 + lk * 4]);

            float p = 0.f;
            #pragma unroll
            for (int r = 0; r < 4; ++r) {
                p += fast_rcp(1.0f + fast_exp2(__builtin_fmaf(d0[r], -LOG2E, c0[r]))) * w0[r];
                p += fast_rcp(1.0f + fast_exp2(__builtin_fmaf(d1[r], -LOG2E, c1[r]))) * w1[r];
                p += fast_rcp(1.0f + fast_exp2(__builtin_fmaf(d2[r], -LOG2E, c2[r]))) * w2[r];
            }
            p += __shfl_xor(p, 16, 64);
            p += __shfl_xor(p, 32, 64);

            const int n = m * 16 + l15;
            const float wn = (n < NN) ? (b2v + p) : 0.f;
            facc[0] += fqa[t].x * wn; facc[1] += fqa[t].y * wn;
            facc[2] += fqa[t].z * wn; facc[3] += fqa[t].w * wn;
            facc[4] += fqb[t].x * wn; facc[5] += fqb[t].y * wn;
            facc[6] += fqb[t].z * wn; facc[7] += fqb[t].w * wn;
        }
    }

    // ---- reduce facc over the 16 l15-lanes (cols lk*8..lk*8+7) ----
    #pragma unroll
    for (int s = 1; s <= 8; s <<= 1) {
        #pragma unroll
        for (int u = 0; u < 8; ++u)
            facc[u] += __shfl_xor(facc[u], s, 64);
    }
    if (l15 == 0) {
        #pragma unroll
        for (int u = 0; u < 8; ++u)
            red_s[wv * KK + lk * 8 + u] = facc[u];
    }
    __syncthreads();

    if (tid < KK) {
        out[b * KK + tid] = red_s[tid] + red_s[KK + tid] +
                            red_s[2 * KK + tid] + red_s[3 * KK + tid];
    }
}

extern "C" void kernel_launch(void* const* d_in, const int* in_sizes, int n_in,
                              void* d_out, int out_size, void* d_ws, size_t ws_size,
                              hipStream_t stream) {
    const float* cad   = (const float*)d_in[0];
    const float* goods = (const float*)d_in[1];
    const float* W1    = (const float*)d_in[2];
    const float* b1    = (const float*)d_in[3];
    const float* W2    = (const float*)d_in[4];
    const float* b2    = (const float*)d_in[5];
    float* outp = (float*)d_out;

    din_kernel<<<BB, 256, 0, stream>>>(cad, goods, W1, b1, W2, b2, outp);
}

// Round 4
// 37.659 us; speedup vs baseline: 1.2298x; 1.2298x over previous
//
#include <hip/hip_runtime.h>

// DIN scorer, fused single kernel, fully collapsed epilogue (R3 structure,
// spill fix: launch_bounds back to (256,4) -- grid is 1024 = exactly 4
// blocks/CU, so >4 blocks/CU is unreachable and the tighter VGPR cap only
// caused scratch spills: R3 counters showed VGPR=40, WRITE_SIZE=54MB).
//   V[j,h] = W1[1152+j*36+h] + sum_i k_i W1[2304+1152*i+j*36+h]   (bf16 LDS V16)
//   cpre[h] = -(b1[h] + sum_i k_i W1[i*36+h]) * LOG2E              (merged in Phase B)
//   Z = Q(200x32).V(32x36) via swapped mfma_f32_16x16x32_bf16: D[row=h,col=n]
//   w[n] = b2 + sum_h sigmoid(Z)*W2[h]   -> per-lane after 2 shfls,
//   out[col] accumulated in the tile loop from the same fp32 fragments.

#define BB 1024
#define NN 200
#define KK 32
#define HID 36
#define QP 40
#define LOG2E 1.44269504f

typedef __attribute__((ext_vector_type(8))) short bf16x8;
typedef __attribute__((ext_vector_type(4))) float f32x4;

__device__ __forceinline__ float rfl(float x) {
    return __uint_as_float(__builtin_amdgcn_readfirstlane(__float_as_uint(x)));
}
__device__ __forceinline__ unsigned short f2bf(float x) {   // RNE f32->bf16
    unsigned int u = __float_as_uint(x);
    u = (u + 0x7fffu + ((u >> 16) & 1u)) >> 16;
    return (unsigned short)u;
}
__device__ __forceinline__ unsigned int pk_bf16(float lo, float hi) { // RNE pack
    unsigned int r;
    asm("v_cvt_pk_bf16_f32 %0, %1, %2" : "=v"(r) : "v"(lo), "v"(hi));
    return r;
}
__device__ __forceinline__ float fast_rcp(float x) {
#if __has_builtin(__builtin_amdgcn_rcpf)
    return __builtin_amdgcn_rcpf(x);
#else
    return 1.0f / x;
#endif
}
__device__ __forceinline__ float fast_exp2(float x) {
#if __has_builtin(__builtin_amdgcn_exp2f)
    return __builtin_amdgcn_exp2f(x);
#else
    return exp2f(x);
#endif
}

__global__ __launch_bounds__(256, 4) void din_kernel(
    const float* __restrict__ cad,    // [B,K]
    const float* __restrict__ goods,  // [B,N,K]
    const float* __restrict__ W1,     // [1088*36]
    const float* __restrict__ b1,     // [36]
    const float* __restrict__ W2,     // [36]
    const float* __restrict__ b2,     // [1]
    float* __restrict__ out)          // [B,K]
{
    __shared__ alignas(16) unsigned short V16[48 * QP];   // [h][j] bf16, rows 36..47 zero
    __shared__ alignas(16) float c48[48];                 // -c*LOG2E, padded 0
    __shared__ alignas(16) float w248[48];                // W2 padded 0
    __shared__ alignas(16) float red_s[4 * KK];

    const int tid  = threadIdx.x;
    const int b    = blockIdx.x;
    const int lane = tid & 63;
    const int wv   = tid >> 6;
    const int l15  = lane & 15, lk = lane >> 4;

    // ---- k -> SGPRs (critical for Phase B; issue first) ----
    const float4* kb4 = reinterpret_cast<const float4*>(cad + b * KK);
    float ks[KK];
    #pragma unroll
    for (int t = 0; t < 8; ++t) {
        const float4 kv = kb4[t];
        ks[4*t+0] = rfl(kv.x); ks[4*t+1] = rfl(kv.y);
        ks[4*t+2] = rfl(kv.z); ks[4*t+3] = rfl(kv.w);
    }
    const float b2v = rfl(b2[0]);

    // ---- goods fragment prefetch: THE HBM stream (each elem read exactly once) ----
    const float* gb = goods + (size_t)b * NN * KK;
    float4 fqa[4], fqb[4];
    #pragma unroll
    for (int t = 0; t < 4; ++t) {
        const int m = wv + 4 * t;
        if (m < 13) {
            int row = m * 16 + l15;
            row = (row < NN) ? row : (NN - 1);
            const float4* qp = reinterpret_cast<const float4*>(gb + row * KK + lk * 8);
            fqa[t] = qp[0];
            fqb[t] = qp[1];
        }
    }

    // ---- Phase B: V (288 float4) + c (9 float4) in one i-loop ----
    {
        const float4* W1q = reinterpret_cast<const float4*>(W1);
        float4 acc0 = W1q[288 + tid];                       // bias rows (W1+1152)
        const bool has1 = (tid < 32);
        const bool hasC = (tid >= 32) && (tid < 41);
        const int  hq   = tid - 32;
        float4 acc1 = make_float4(0.f, 0.f, 0.f, 0.f);
        float4 accC = make_float4(0.f, 0.f, 0.f, 0.f);
        if (has1) acc1 = W1q[288 + 256 + tid];
        if (hasC) accC = reinterpret_cast<const float4*>(b1)[hq];

        #pragma unroll 4
        for (int i = 0; i < KK; ++i) {
            const float ki = ks[i];
            const float4* W1o = W1q + 576 + 288 * i;        // W1 + 2304 + 1152*i
            const float4 w0 = W1o[tid];
            acc0.x += ki * w0.x; acc0.y += ki * w0.y;
            acc0.z += ki * w0.z; acc0.w += ki * w0.w;
            if (has1) {
                const float4 w1v = W1o[256 + tid];
                acc1.x += ki * w1v.x; acc1.y += ki * w1v.y;
                acc1.z += ki * w1v.z; acc1.w += ki * w1v.w;
            }
            if (hasC) {
                const float4 wc = W1q[i * 9 + hq];          // W1[i*36 + 4*hq ..]
                accC.x += ki * wc.x; accC.y += ki * wc.y;
                accC.z += ki * wc.z; accC.w += ki * wc.w;
            }
        }

        // scatter V -> bf16 LDS
        {
            const float a0[4] = {acc0.x, acc0.y, acc0.z, acc0.w};
            #pragma unroll
            for (int q = 0; q < 4; ++q) {
                const int e = 4 * tid + q, j = e / 36, h = e - 36 * j;
                V16[h * QP + j] = f2bf(a0[q]);
            }
            if (has1) {
                const float a1[4] = {acc1.x, acc1.y, acc1.z, acc1.w};
                #pragma unroll
                for (int q = 0; q < 4; ++q) {
                    const int e = 1024 + 4 * tid + q, j = e / 36, h = e - 36 * j;
                    V16[h * QP + j] = f2bf(a1[q]);
                }
            }
        }
        // c (premultiplied by -LOG2E), pads, W2 copy + pads
        if (hasC) {
            float4 cp4;
            cp4.x = -accC.x * LOG2E; cp4.y = -accC.y * LOG2E;
            cp4.z = -accC.z * LOG2E; cp4.w = -accC.w * LOG2E;
            *reinterpret_cast<float4*>(&c48[4 * hq]) = cp4;
        }
        if (tid >= 41 && tid < 44)
            *reinterpret_cast<float4*>(&c48[36 + 4 * (tid - 41)]) =
                make_float4(0.f, 0.f, 0.f, 0.f);
        if (tid >= 44 && tid < 53)
            *reinterpret_cast<float4*>(&w248[4 * (tid - 44)]) =
                reinterpret_cast<const float4*>(W2)[tid - 44];
        if (tid >= 53 && tid < 56)
            *reinterpret_cast<float4*>(&w248[36 + 4 * (tid - 53)]) =
                make_float4(0.f, 0.f, 0.f, 0.f);
        // V16 pad rows h=36..47 (j 0..31)
        if (tid < 192) {
            unsigned int* v32 = reinterpret_cast<unsigned int*>(V16);
            v32[(36 + (tid >> 4)) * (QP / 2) + (tid & 15)] = 0u;
        }
    }
    __syncthreads();   // V16, c48, w248 ready

    // ---- per-lane V fragments (MFMA A-operand) + hoisted h-constants ----
    bf16x8 bfrag[3];
    f32x4 cc[3], ww[3];
    #pragma unroll
    for (int nt = 0; nt < 3; ++nt) {
        bfrag[nt] = *reinterpret_cast<const bf16x8*>(&V16[(nt * 16 + l15) * QP + lk * 8]);
        cc[nt] = *reinterpret_cast<const f32x4*>(&c48[nt * 16 + lk * 4]);
        ww[nt] = *reinterpret_cast<const f32x4*>(&w248[nt * 16 + lk * 4]);
    }

    // ---- tile loop: MFMA -> sigmoid -> w_n -> fused out-accumulation ----
    float facc[8] = {0.f, 0.f, 0.f, 0.f, 0.f, 0.f, 0.f, 0.f};
    #pragma unroll
    for (int t = 0; t < 4; ++t) {
        const int m = wv + 4 * t;
        if (m < 13) {
            union { unsigned int u[4]; bf16x8 v; } aq;
            aq.u[0] = pk_bf16(fqa[t].x, fqa[t].y);
            aq.u[1] = pk_bf16(fqa[t].z, fqa[t].w);
            aq.u[2] = pk_bf16(fqb[t].x, fqb[t].y);
            aq.u[3] = pk_bf16(fqb[t].z, fqb[t].w);
            const f32x4 zero = {0.f, 0.f, 0.f, 0.f};
            const f32x4 d0 = __builtin_amdgcn_mfma_f32_16x16x32_bf16(bfrag[0], aq.v, zero, 0, 0, 0);
            const f32x4 d1 = __builtin_amdgcn_mfma_f32_16x16x32_bf16(bfrag[1], aq.v, zero, 0, 0, 0);
            const f32x4 d2 = __builtin_amdgcn_mfma_f32_16x16x32_bf16(bfrag[2], aq.v, zero, 0, 0, 0);

            float p = 0.f;
            #pragma unroll
            for (int r = 0; r < 4; ++r) {
                p += fast_rcp(1.0f + fast_exp2(__builtin_fmaf(d0[r], -LOG2E, cc[0][r]))) * ww[0][r];
                p += fast_rcp(1.0f + fast_exp2(__builtin_fmaf(d1[r], -LOG2E, cc[1][r]))) * ww[1][r];
                p += fast_rcp(1.0f + fast_exp2(__builtin_fmaf(d2[r], -LOG2E, cc[2][r]))) * ww[2][r];
            }
            p += __shfl_xor(p, 16, 64);
            p += __shfl_xor(p, 32, 64);

            const int n = m * 16 + l15;
            const float wn = (n < NN) ? (b2v + p) : 0.f;
            facc[0] += fqa[t].x * wn; facc[1] += fqa[t].y * wn;
            facc[2] += fqa[t].z * wn; facc[3] += fqa[t].w * wn;
            facc[4] += fqb[t].x * wn; facc[5] += fqb[t].y * wn;
            facc[6] += fqb[t].z * wn; facc[7] += fqb[t].w * wn;
        }
    }

    // ---- reduce facc over the 16 l15-lanes (cols lk*8..lk*8+7) ----
    #pragma unroll
    for (int s = 1; s <= 8; s <<= 1) {
        #pragma unroll
        for (int u = 0; u < 8; ++u)
            facc[u] += __shfl_xor(facc[u], s, 64);
    }
    if (l15 == 0) {
        #pragma unroll
        for (int u = 0; u < 8; ++u)
            red_s[wv * KK + lk * 8 + u] = facc[u];
    }
    __syncthreads();

    if (tid < KK) {
        out[b * KK + tid] = red_s[tid] + red_s[KK + tid] +
                            red_s[2 * KK + tid] + red_s[3 * KK + tid];
    }
}

extern "C" void kernel_launch(void* const* d_in, const int* in_sizes, int n_in,
                              void* d_out, int out_size, void* d_ws, size_t ws_size,
                              hipStream_t stream) {
    const float* cad   = (const float*)d_in[0];
    const float* goods = (const float*)d_in[1];
    const float* W1    = (const float*)d_in[2];
    const float* b1    = (const float*)d_in[3];
    const float* W2    = (const float*)d_in[4];
    const float* b2    = (const float*)d_in[5];
    float* outp = (float*)d_out;

    din_kernel<<<BB, 256, 0, stream>>>(cad, goods, W1, b1, W2, b2, outp);
}

// Round 5
// 27.631 us; speedup vs baseline: 1.6761x; 1.3629x over previous
//
#include <hip/hip_runtime.h>

// DIN scorer, two-kernel split v2:
//   prep (256 blocks x 4 b): V_b = bias + sum_i k_i W1_i  (batched, W1 staged in
//     LDS; 40MB L2 traffic total instead of 160MB), emitted as bf16 MFMA
//     fragments Vw[b][nt][lane][8]; Cw[b][48] = -(b1 + W1c k)*log2e padded;
//     W2p[48] = W2 padded.
//   main (1024 blocks): NO Phase B -> short critical path, one barrier.
//     Z = Q(200x32).V(32x36) via swapped mfma_f32_16x16x32_bf16 (D[row=h,col=n]),
//     w[n] = b2 + sum_h sigmoid(Z+c)*W2  (2 shfl), out accumulated in tile loop.

#define BB 1024
#define NN 200
#define KK 32
#define HID 36
#define QP 40
#define LOG2E 1.44269504f
#define PREP_BPB 4
#define PREP_BLOCKS (BB / PREP_BPB)

typedef __attribute__((ext_vector_type(8))) short bf16x8;
typedef __attribute__((ext_vector_type(4))) float f32x4;

__device__ __forceinline__ float rfl(float x) {
    return __uint_as_float(__builtin_amdgcn_readfirstlane(__float_as_uint(x)));
}
__device__ __forceinline__ unsigned short f2bf(float x) {   // RNE f32->bf16
    unsigned int u = __float_as_uint(x);
    u = (u + 0x7fffu + ((u >> 16) & 1u)) >> 16;
    return (unsigned short)u;
}
__device__ __forceinline__ unsigned int pk_bf16(float lo, float hi) { // RNE pack
    unsigned int r;
    asm("v_cvt_pk_bf16_f32 %0, %1, %2" : "=v"(r) : "v"(lo), "v"(hi));
    return r;
}
__device__ __forceinline__ float fast_rcp(float x) {
#if __has_builtin(__builtin_amdgcn_rcpf)
    return __builtin_amdgcn_rcpf(x);
#else
    return 1.0f / x;
#endif
}
__device__ __forceinline__ float fast_exp2(float x) {
#if __has_builtin(__builtin_amdgcn_exp2f)
    return __builtin_amdgcn_exp2f(x);
#else
    return exp2f(x);
#endif
}

// ---------------- prep: V fragments + c + padded W2, for all b ----------------
__global__ __launch_bounds__(256) void din_prep(
    const float* __restrict__ cad,    // [B,K]
    const float* __restrict__ W1,     // [1088*36]
    const float* __restrict__ b1,     // [36]
    const float* __restrict__ W2,     // [36]
    unsigned short* __restrict__ Vw,  // [B][3][64][8] bf16
    float* __restrict__ Cw,           // [B][48] f32 (-c*log2e, zero-padded)
    float* __restrict__ W2p)          // [48]
{
    __shared__ float4 W1c[8 * 288];                        // 36864 B
    __shared__ unsigned short V16s[PREP_BPB * 48 * QP];    // 15360 B

    const int tid = threadIdx.x;
    const int b0  = blockIdx.x * PREP_BPB;
    const bool two = (tid < 32);

    const float4* W1q = reinterpret_cast<const float4*>(W1);

    float4 a0[PREP_BPB], a1[PREP_BPB];
    {
        const float4 bias0 = W1q[288 + tid];
        float4 bias1 = make_float4(0.f, 0.f, 0.f, 0.f);
        if (two) bias1 = W1q[288 + 256 + tid];
        #pragma unroll
        for (int bl = 0; bl < PREP_BPB; ++bl) { a0[bl] = bias0; a1[bl] = bias1; }
    }

    #pragma unroll 1
    for (int c = 0; c < 4; ++c) {
        #pragma unroll
        for (int ci = 0; ci < 8; ++ci) {
            W1c[ci * 288 + tid] = W1q[576 + 288 * (8 * c + ci) + tid];
            if (two) W1c[ci * 288 + 256 + tid] = W1q[576 + 288 * (8 * c + ci) + 256 + tid];
        }
        float kk[PREP_BPB][8];
        #pragma unroll
        for (int bl = 0; bl < PREP_BPB; ++bl)
            #pragma unroll
            for (int ci = 0; ci < 8; ++ci)
                kk[bl][ci] = cad[(b0 + bl) * KK + c * 8 + ci];
        __syncthreads();
        #pragma unroll
        for (int ci = 0; ci < 8; ++ci) {
            const float4 w0 = W1c[ci * 288 + tid];
            #pragma unroll
            for (int bl = 0; bl < PREP_BPB; ++bl) {
                a0[bl].x += kk[bl][ci] * w0.x;
                a0[bl].y += kk[bl][ci] * w0.y;
                a0[bl].z += kk[bl][ci] * w0.z;
                a0[bl].w += kk[bl][ci] * w0.w;
            }
            if (two) {
                const float4 w1 = W1c[ci * 288 + 256 + tid];
                #pragma unroll
                for (int bl = 0; bl < PREP_BPB; ++bl) {
                    a1[bl].x += kk[bl][ci] * w1.x;
                    a1[bl].y += kk[bl][ci] * w1.y;
                    a1[bl].z += kk[bl][ci] * w1.z;
                    a1[bl].w += kk[bl][ci] * w1.w;
                }
            }
        }
        __syncthreads();
    }

    // scatter acc -> V16s[bl][h*QP + j] bf16
    {
        #pragma unroll
        for (int bl = 0; bl < PREP_BPB; ++bl) {
            const float arr[4] = {a0[bl].x, a0[bl].y, a0[bl].z, a0[bl].w};
            #pragma unroll
            for (int q = 0; q < 4; ++q) {
                const int e = 4 * tid + q, j = e / 36, h = e - 36 * j;
                V16s[bl * (48 * QP) + h * QP + j] = f2bf(arr[q]);
            }
        }
        if (two) {
            #pragma unroll
            for (int bl = 0; bl < PREP_BPB; ++bl) {
                const float arr[4] = {a1[bl].x, a1[bl].y, a1[bl].z, a1[bl].w};
                #pragma unroll
                for (int q = 0; q < 4; ++q) {
                    const int e = 1024 + 4 * tid + q, j = e / 36, h = e - 36 * j;
                    V16s[bl * (48 * QP) + h * QP + j] = f2bf(arr[q]);
                }
            }
        }
    }
    // zero pad rows h=36..47
    {
        unsigned int* v32 = reinterpret_cast<unsigned int*>(V16s);
        #pragma unroll
        for (int r = 0; r < 4; ++r) {
            const int p = tid + 256 * r;
            if (p < PREP_BPB * 240) {
                const int bl = p / 240, o = p % 240;
                v32[bl * 960 + 720 + o] = 0u;
            }
        }
    }
    __syncthreads();

    // coalesced fragment gather+write: unit u (16B) = [bl][nt][lane]
    #pragma unroll
    for (int pass = 0; pass < 3; ++pass) {
        const int u  = tid + 256 * pass;              // < 768
        const int bl = u / 192, r = u % 192;
        const int nt = r >> 6, l = r & 63;
        const bf16x8 vv = *reinterpret_cast<const bf16x8*>(
            &V16s[bl * (48 * QP) + (nt * 16 + (l & 15)) * QP + (l >> 4) * 8]);
        *reinterpret_cast<bf16x8*>(Vw + ((size_t)b0 * 192 + u) * 8) = vv;
    }

    // c[b][48] = -(b1 + W1c k)*log2e, padded
    if (tid < PREP_BPB * 48) {
        const int bl = tid / 48, h = tid % 48;
        float s = 0.f;
        if (h < HID) {
            s = b1[h];
            #pragma unroll
            for (int i = 0; i < KK; ++i)
                s += cad[(b0 + bl) * KK + i] * W1[i * HID + h];
        }
        Cw[(b0 + bl) * 48 + h] = -s * LOG2E;
    }
    if (blockIdx.x == 0 && tid < 48)
        W2p[tid] = (tid < HID) ? W2[tid] : 0.f;
}

// ---------------- main: short critical path, one barrier ----------------
__global__ __launch_bounds__(256, 4) void din_main(
    const float* __restrict__ goods,  // [B,N,K]
    const float* __restrict__ b2,     // [1]
    const unsigned short* __restrict__ Vw,
    const float* __restrict__ Cw,
    const float* __restrict__ W2p,
    float* __restrict__ out)          // [B,K]
{
    __shared__ alignas(16) float red_s[4 * KK];

    const int tid  = threadIdx.x;
    const int b    = blockIdx.x;
    const int lane = tid & 63;
    const int wv   = tid >> 6;
    const int l15  = lane & 15, lk = lane >> 4;

    // V fragments + h-constants (L2/L3-hot, coalesced 16B)
    bf16x8 bfrag[3];
    f32x4 cc[3], ww[3];
    #pragma unroll
    for (int nt = 0; nt < 3; ++nt) {
        bfrag[nt] = *reinterpret_cast<const bf16x8*>(Vw + ((size_t)b * 192 + nt * 64 + lane) * 8);
        cc[nt] = *reinterpret_cast<const f32x4*>(Cw + b * 48 + nt * 16 + lk * 4);
        ww[nt] = *reinterpret_cast<const f32x4*>(W2p + nt * 16 + lk * 4);
    }
    const float b2v = rfl(b2[0]);

    // tile loop: goods fragment load -> MFMA -> sigmoid -> w_n -> fused out-acc
    const float* gb = goods + (size_t)b * NN * KK;
    float facc[8] = {0.f, 0.f, 0.f, 0.f, 0.f, 0.f, 0.f, 0.f};
    #pragma unroll
    for (int t = 0; t < 4; ++t) {
        const int m = wv + 4 * t;
        if (m < 13) {
            int row = m * 16 + l15;
            row = (row < NN) ? row : (NN - 1);
            const float4* qp = reinterpret_cast<const float4*>(gb + row * KK + lk * 8);
            const float4 qa = qp[0], qb = qp[1];

            union { unsigned int u[4]; bf16x8 v; } aq;
            aq.u[0] = pk_bf16(qa.x, qa.y);
            aq.u[1] = pk_bf16(qa.z, qa.w);
            aq.u[2] = pk_bf16(qb.x, qb.y);
            aq.u[3] = pk_bf16(qb.z, qb.w);
            const f32x4 zero = {0.f, 0.f, 0.f, 0.f};
            const f32x4 d0 = __builtin_amdgcn_mfma_f32_16x16x32_bf16(bfrag[0], aq.v, zero, 0, 0, 0);
            const f32x4 d1 = __builtin_amdgcn_mfma_f32_16x16x32_bf16(bfrag[1], aq.v, zero, 0, 0, 0);
            const f32x4 d2 = __builtin_amdgcn_mfma_f32_16x16x32_bf16(bfrag[2], aq.v, zero, 0, 0, 0);

            float p = 0.f;
            #pragma unroll
            for (int r = 0; r < 4; ++r) {
                p += fast_rcp(1.0f + fast_exp2(__builtin_fmaf(d0[r], -LOG2E, cc[0][r]))) * ww[0][r];
                p += fast_rcp(1.0f + fast_exp2(__builtin_fmaf(d1[r], -LOG2E, cc[1][r]))) * ww[1][r];
                p += fast_rcp(1.0f + fast_exp2(__builtin_fmaf(d2[r], -LOG2E, cc[2][r]))) * ww[2][r];
            }
            p += __shfl_xor(p, 16, 64);
            p += __shfl_xor(p, 32, 64);

            const int n = m * 16 + l15;
            const float wn = (n < NN) ? (b2v + p) : 0.f;
            facc[0] += qa.x * wn; facc[1] += qa.y * wn;
            facc[2] += qa.z * wn; facc[3] += qa.w * wn;
            facc[4] += qb.x * wn; facc[5] += qb.y * wn;
            facc[6] += qb.z * wn; facc[7] += qb.w * wn;
        }
    }

    // reduce facc over the 16 l15-lanes (cols lk*8..lk*8+7)
    #pragma unroll
    for (int s = 1; s <= 8; s <<= 1) {
        #pragma unroll
        for (int u = 0; u < 8; ++u)
            facc[u] += __shfl_xor(facc[u], s, 64);
    }
    if (l15 == 0) {
        #pragma unroll
        for (int u = 0; u < 8; ++u)
            red_s[wv * KK + lk * 8 + u] = facc[u];
    }
    __syncthreads();

    if (tid < KK) {
        out[b * KK + tid] = red_s[tid] + red_s[KK + tid] +
                            red_s[2 * KK + tid] + red_s[3 * KK + tid];
    }
}

extern "C" void kernel_launch(void* const* d_in, const int* in_sizes, int n_in,
                              void* d_out, int out_size, void* d_ws, size_t ws_size,
                              hipStream_t stream) {
    const float* cad   = (const float*)d_in[0];
    const float* goods = (const float*)d_in[1];
    const float* W1    = (const float*)d_in[2];
    const float* b1    = (const float*)d_in[3];
    const float* W2    = (const float*)d_in[4];
    const float* b2    = (const float*)d_in[5];
    float* outp = (float*)d_out;

    unsigned short* Vw = (unsigned short*)d_ws;                       // 3 MiB
    float* Cw  = (float*)((char*)d_ws + (size_t)BB * 192 * 16);       // 192 KiB
    float* W2p = Cw + (size_t)BB * 48;                                // 192 B

    din_prep<<<PREP_BLOCKS, 256, 0, stream>>>(cad, W1, b1, W2, Vw, Cw, W2p);
    din_main<<<BB, 256, 0, stream>>>(goods, b2, Vw, Cw, W2p, outp);
}

// Round 6
// 22.051 us; speedup vs baseline: 2.1002x; 1.2531x over previous
//
#include <hip/hip_runtime.h>

// DIN scorer, fused, 512-thread blocks (occupancy play):
//   grid 1024 x 512 thr = 2048 thr/CU = 32 waves/CU if VGPR<=64 (vs 16 before).
//   V[j,h] = W1[1152+j*36+h] + sum_i k_i W1[2304+1152*i+j*36+h]   (bf16 LDS V16)
//   cpre[h] = -(b1[h] + sum_i k_i W1[i*36+h]) * LOG2E
//   Z = Q(200x32).V(32x36) via swapped mfma_f32_16x16x32_bf16: D[row=h,col=n]
//   w[n] = b2 + sum_h sigmoid(Z+c)*W2[h]  (2 shfl), out accumulated in tile loop.
//   8 waves: wave wv does tile m=wv (rows<128, unmasked) and m=wv+8 if wv<5.
//   Register diet: per-thread Phase-B acc = 1 float4; goods prefetch 8-16 VGPR;
//   c/W2 read from LDS per tile (broadcast) instead of hoisted VGPRs.

#define BB 1024
#define NN 200
#define KK 32
#define HID 36
#define QP 40
#define LOG2E 1.44269504f

typedef __attribute__((ext_vector_type(8))) short bf16x8;
typedef __attribute__((ext_vector_type(4))) float f32x4;

__device__ __forceinline__ float rfl(float x) {
    return __uint_as_float(__builtin_amdgcn_readfirstlane(__float_as_uint(x)));
}
__device__ __forceinline__ unsigned short f2bf(float x) {   // RNE f32->bf16
    unsigned int u = __float_as_uint(x);
    u = (u + 0x7fffu + ((u >> 16) & 1u)) >> 16;
    return (unsigned short)u;
}
__device__ __forceinline__ unsigned int pk_bf16(float lo, float hi) { // RNE pack
    unsigned int r;
    asm("v_cvt_pk_bf16_f32 %0, %1, %2" : "=v"(r) : "v"(lo), "v"(hi));
    return r;
}
__device__ __forceinline__ float fast_rcp(float x) {
#if __has_builtin(__builtin_amdgcn_rcpf)
    return __builtin_amdgcn_rcpf(x);
#else
    return 1.0f / x;
#endif
}
__device__ __forceinline__ float fast_exp2(float x) {
#if __has_builtin(__builtin_amdgcn_exp2f)
    return __builtin_amdgcn_exp2f(x);
#else
    return exp2f(x);
#endif
}

__global__ __launch_bounds__(512, 4) void din_kernel(
    const float* __restrict__ cad,    // [B,K]
    const float* __restrict__ goods,  // [B,N,K]
    const float* __restrict__ W1,     // [1088*36]
    const float* __restrict__ b1,     // [36]
    const float* __restrict__ W2,     // [36]
    const float* __restrict__ b2,     // [1]
    float* __restrict__ out)          // [B,K]
{
    __shared__ alignas(16) unsigned short V16[48 * QP];   // [h][j] bf16, rows 36..47 zero
    __shared__ alignas(16) float c48[48];                 // -c*LOG2E, padded 0
    __shared__ alignas(16) float w248[48];                // W2 padded 0
    __shared__ alignas(16) float red_s[8 * KK];

    const int tid  = threadIdx.x;
    const int b    = blockIdx.x;
    const int lane = tid & 63;
    const int wv   = tid >> 6;
    const int l15  = lane & 15, lk = lane >> 4;

    const float* gb = goods + (size_t)b * NN * KK;

    // ---- goods fragment prefetch: issue the HBM stream first ----
    // tile 0: m = wv, rows wv*16+l15 < 128 < 200 -> no clamp, no mask.
    float4 fq0a, fq0b;
    {
        const float4* qp = reinterpret_cast<const float4*>(gb + (wv * 16 + l15) * KK + lk * 8);
        fq0a = qp[0]; fq0b = qp[1];
    }
    // tile 1 (wv<5): m = wv+8, rows 128..207 -> clamp, mask at use.
    float4 fq1a = make_float4(0.f, 0.f, 0.f, 0.f), fq1b = fq1a;
    if (wv < 5) {
        int row = (wv + 8) * 16 + l15;
        row = (row < NN) ? row : (NN - 1);
        const float4* qp = reinterpret_cast<const float4*>(gb + row * KK + lk * 8);
        fq1a = qp[0]; fq1b = qp[1];
    }

    // ---- k -> SGPRs (only Phase-B waves need it) ----
    float ks[KK];
    if (wv < 5) {
        const float4* kb4 = reinterpret_cast<const float4*>(cad + b * KK);
        #pragma unroll
        for (int t = 0; t < 8; ++t) {
            const float4 kv = kb4[t];
            ks[4*t+0] = rfl(kv.x); ks[4*t+1] = rfl(kv.y);
            ks[4*t+2] = rfl(kv.z); ks[4*t+3] = rfl(kv.w);
        }
    }
    const float b2v = rfl(b2[0]);

    // ---- Phase B: V (288 owners) + c (9 owners) + pads, one barrier ----
    const float4* W1q = reinterpret_cast<const float4*>(W1);
    if (tid < 288) {
        float4 acc = W1q[288 + tid];                    // bias row (W1+1152)
        #pragma unroll 4
        for (int i = 0; i < KK; ++i) {
            const float ki = ks[i];
            const float4 w0 = W1q[576 + 288 * i + tid];
            acc.x += ki * w0.x; acc.y += ki * w0.y;
            acc.z += ki * w0.z; acc.w += ki * w0.w;
        }
        const float arr[4] = {acc.x, acc.y, acc.z, acc.w};
        #pragma unroll
        for (int q = 0; q < 4; ++q) {
            const int e = 4 * tid + q, j = e / 36, h = e - 36 * j;
            V16[h * QP + j] = f2bf(arr[q]);
        }
    } else if (tid < 297) {                             // c quads
        const int hq = tid - 288;
        float4 acc = reinterpret_cast<const float4*>(b1)[hq];
        #pragma unroll 4
        for (int i = 0; i < KK; ++i) {
            const float ki = ks[i];
            const float4 wc = W1q[i * 9 + hq];          // W1[i*36 + 4*hq ..]
            acc.x += ki * wc.x; acc.y += ki * wc.y;
            acc.z += ki * wc.z; acc.w += ki * wc.w;
        }
        float4 cp4;
        cp4.x = -acc.x * LOG2E; cp4.y = -acc.y * LOG2E;
        cp4.z = -acc.z * LOG2E; cp4.w = -acc.w * LOG2E;
        *reinterpret_cast<float4*>(&c48[4 * hq]) = cp4;
    } else if (tid < 300) {                             // c pad 36..47
        *reinterpret_cast<float4*>(&c48[36 + 4 * (tid - 297)]) =
            make_float4(0.f, 0.f, 0.f, 0.f);
    } else if (tid < 309) {                             // W2 copy (9 quads)
        *reinterpret_cast<float4*>(&w248[4 * (tid - 300)]) =
            reinterpret_cast<const float4*>(W2)[tid - 300];
    } else if (tid < 312) {                             // W2 pad 36..47
        *reinterpret_cast<float4*>(&w248[36 + 4 * (tid - 309)]) =
            make_float4(0.f, 0.f, 0.f, 0.f);
    } else if (tid < 504) {                             // V16 pad rows 36..47
        const int r = tid - 312;                        // 0..191
        reinterpret_cast<unsigned int*>(V16)[(36 + (r >> 4)) * (QP / 2) + (r & 15)] = 0u;
    }
    __syncthreads();   // V16, c48, w248 ready

    // ---- per-lane V fragments (MFMA A-operand) ----
    bf16x8 bfrag[3];
    #pragma unroll
    for (int nt = 0; nt < 3; ++nt)
        bfrag[nt] = *reinterpret_cast<const bf16x8*>(&V16[(nt * 16 + l15) * QP + lk * 8]);

    // ---- tile bodies: MFMA -> sigmoid -> w_n -> fused out-accumulation ----
    float facc[8] = {0.f, 0.f, 0.f, 0.f, 0.f, 0.f, 0.f, 0.f};

    auto tile = [&](const float4& qa, const float4& qb, int m, bool masked) {
        union { unsigned int u[4]; bf16x8 v; } aq;
        aq.u[0] = pk_bf16(qa.x, qa.y);
        aq.u[1] = pk_bf16(qa.z, qa.w);
        aq.u[2] = pk_bf16(qb.x, qb.y);
        aq.u[3] = pk_bf16(qb.z, qb.w);
        const f32x4 zero = {0.f, 0.f, 0.f, 0.f};
        const f32x4 d0 = __builtin_amdgcn_mfma_f32_16x16x32_bf16(bfrag[0], aq.v, zero, 0, 0, 0);
        const f32x4 d1 = __builtin_amdgcn_mfma_f32_16x16x32_bf16(bfrag[1], aq.v, zero, 0, 0, 0);
        const f32x4 d2 = __builtin_amdgcn_mfma_f32_16x16x32_bf16(bfrag[2], aq.v, zero, 0, 0, 0);

        const f32x4 c0 = *reinterpret_cast<const f32x4*>(&c48[lk * 4]);
        const f32x4 w0 = *reinterpret_cast<const f32x4*>(&w248[lk * 4]);
        const f32x4 c1 = *reinterpret_cast<const f32x4*>(&c48[16 + lk * 4]);
        const f32x4 w1 = *reinterpret_cast<const f32x4*>(&w248[16 + lk * 4]);
        const f32x4 c2 = *reinterpret_cast<const f32x4*>(&c48[32 + lk * 4]);
        const f32x4 w2 = *reinterpret_cast<const f32x4*>(&w248[32 + lk * 4]);

        float p = 0.f;
        #pragma unroll
        for (int r = 0; r < 4; ++r) {
            p += fast_rcp(1.0f + fast_exp2(__builtin_fmaf(d0[r], -LOG2E, c0[r]))) * w0[r];
            p += fast_rcp(1.0f + fast_exp2(__builtin_fmaf(d1[r], -LOG2E, c1[r]))) * w1[r];
            p += fast_rcp(1.0f + fast_exp2(__builtin_fmaf(d2[r], -LOG2E, c2[r]))) * w2[r];
        }
        p += __shfl_xor(p, 16, 64);
        p += __shfl_xor(p, 32, 64);

        float wn = b2v + p;
        if (masked) {
            const int n = m * 16 + l15;
            wn = (n < NN) ? wn : 0.f;
        }
        facc[0] += qa.x * wn; facc[1] += qa.y * wn;
        facc[2] += qa.z * wn; facc[3] += qa.w * wn;
        facc[4] += qb.x * wn; facc[5] += qb.y * wn;
        facc[6] += qb.z * wn; facc[7] += qb.w * wn;
    };

    tile(fq0a, fq0b, wv, false);
    if (wv < 5) tile(fq1a, fq1b, wv + 8, true);

    // ---- reduce facc over the 16 l15-lanes (cols lk*8..lk*8+7) ----
    #pragma unroll
    for (int s = 1; s <= 8; s <<= 1) {
        #pragma unroll
        for (int u = 0; u < 8; ++u)
            facc[u] += __shfl_xor(facc[u], s, 64);
    }
    if (l15 == 0) {
        #pragma unroll
        for (int u = 0; u < 8; ++u)
            red_s[wv * KK + lk * 8 + u] = facc[u];
    }
    __syncthreads();

    if (tid < KK) {
        float s = 0.f;
        #pragma unroll
        for (int w = 0; w < 8; ++w) s += red_s[w * KK + tid];
        out[b * KK + tid] = s;
    }
}

extern "C" void kernel_launch(void* const* d_in, const int* in_sizes, int n_in,
                              void* d_out, int out_size, void* d_ws, size_t ws_size,
                              hipStream_t stream) {
    const float* cad   = (const float*)d_in[0];
    const float* goods = (const float*)d_in[1];
    const float* W1    = (const float*)d_in[2];
    const float* b1    = (const float*)d_in[3];
    const float* W2    = (const float*)d_in[4];
    const float* b2    = (const float*)d_in[5];
    float* outp = (float*)d_out;

    din_kernel<<<BB, 512, 0, stream>>>(cad, goods, W1, b1, W2, b2, outp);
}